// Round 12
// baseline (732.728 us; speedup 1.0000x reference)
//
#include <hip/hip_runtime.h>
#include <hip/hip_fp16.h>

#define HID 64
#define IN_DIM 34
#define NCLS 10
#define BLK 128
#define SSTR 17   // staging tile row stride (odd -> conflict-free col reads)
#define NPW 4     // node_mlp: nodes per wave (weight-reg amortization)

// ---------- helpers ----------

__device__ __forceinline__ unsigned enc_f(float f) {
    unsigned u = __float_as_uint(f);
    return (u & 0x80000000u) ? ~u : (u | 0x80000000u);
}
__device__ __forceinline__ float dec_f(unsigned u) {
    return __uint_as_float((u & 0x80000000u) ? (u & 0x7FFFFFFFu) : ~u);
}
// readlane: broadcast on the VALU pipe (vs __shfl -> ds_bpermute on the
// DS pipe, which was node_mlp's wall: 9.8M DS ops chip-wide)
__device__ __forceinline__ float rl(float v, int k) {
    return __uint_as_float((unsigned)__builtin_amdgcn_readlane(
        (int)__float_as_uint(v), k));
}

// wave-local LDS fence: DS ops from one wave complete in order; lgkmcnt(0)
// guarantees all prior ds_writes are committed before later ds_reads issue.
#define WAVE_FENCE() do { \
    asm volatile("s_waitcnt lgkmcnt(0)" ::: "memory"); \
    __builtin_amdgcn_sched_barrier(0); \
} while (0)

// ---------- CSR build ----------

__global__ __launch_bounds__(256) void hist_pass(
        const int* __restrict__ ei, int* __restrict__ hist, int E) {
    int e = blockIdx.x * blockDim.x + threadIdx.x;
    if (e >= E) return;
    atomicAdd(&hist[ei[E + e]], 1);
}

__global__ __launch_bounds__(256) void scan1(
        const int* __restrict__ hist, int* __restrict__ loc,
        int* __restrict__ part, int N) {
    __shared__ int sh[256];
    int tid = threadIdx.x;
    int i = blockIdx.x * 256 + tid;
    int v = (i < N) ? hist[i] : 0;
    sh[tid] = v;
    __syncthreads();
    for (int d = 1; d < 256; d <<= 1) {
        int t = (tid >= d) ? sh[tid - d] : 0;
        __syncthreads();
        sh[tid] += t;
        __syncthreads();
    }
    if (i < N) loc[i] = sh[tid] - v;          // exclusive
    if (tid == 255) part[blockIdx.x] = sh[255];
}

__global__ __launch_bounds__(512) void scan2(int* __restrict__ part, int NB) {
    __shared__ int sh[512];
    int t = threadIdx.x;
    int v = (t < NB) ? part[t] : 0;
    sh[t] = v;
    __syncthreads();
    for (int d = 1; d < 512; d <<= 1) {
        int u = (t >= d) ? sh[t - d] : 0;
        __syncthreads();
        sh[t] += u;
        __syncthreads();
    }
    if (t < NB) part[t] = sh[t] - v;          // exclusive
}

__global__ __launch_bounds__(256) void scan3(
        const int* __restrict__ loc, const int* __restrict__ part,
        int* __restrict__ offs, int* __restrict__ cursor, int N) {
    int i = blockIdx.x * 256 + threadIdx.x;
    if (i >= N) return;
    int o = loc[i] + part[blockIdx.x];
    offs[i] = o;
    cursor[i] = o;
}

// ROUND 12: back to ONE 16B-aligned record per edge. Round-5's 8B pk +
// 4B srcs split touched TWO 64B lines per edge, each line written by
// 8-16 threads scattered in time AND across XCDs (per-XCD L2s don't
// merge each other's partials) -> 150 MB writeback for 19 MB payload
// (8x amplification, measured round 11; VALUBusy 0.7% = pure memory
// wall). Single int4 store: one line-touch per edge, half the touch
// events, one array's line set instead of two.
// rec = {eid, src, col, port|flag<<16}
__global__ __launch_bounds__(256) void sort_pass(
        const int* __restrict__ ei, const int* __restrict__ ports,
        const int* __restrict__ flags, int* __restrict__ cursor,
        int4* __restrict__ rec, int E) {
    int e = blockIdx.x * blockDim.x + threadIdx.x;
    if (e >= E) return;
    int c = ei[E + e];
    int pos = atomicAdd(&cursor[c], 1);
    int4 r;
    r.x = e;
    r.y = ei[e];
    r.z = c;
    r.w = (int)((unsigned)ports[e] | ((unsigned)flags[e] << 16));
    rec[pos] = r;
}

// ---------- edge hidden-layer + wave-local segmented reduction ----------
// hsum[n] = sum_e relu(ea_e W1 + b1), lsum[n] = sum_e ea_e  (e: col==n).
// Two half-E dispatches (rocprof top-5 visibility; atomics make the split
// boundary correct). Ballot boundary mask in SGPRs (round 10).

__device__ __forceinline__ void strip_reduce16(
        const float* __restrict__ wstg, const int* __restrict__ wcol, int lane,
        unsigned long long bmask,
        float* __restrict__ dst, int dstride, int chbase) {
    // 4 strips of 16 rows; lane&15 owns one staged column.
    int colL = lane & 15;
    int r0 = (lane >> 4) * 16;
    unsigned m16 = (unsigned)(bmask >> r0) & 0xFFFFu;  // uniform per 16-lane group
    float acc = 0.0f;
    int cur = wcol[r0];
    #pragma unroll
    for (int rb = 0; rb < 16; rb += 8) {
        float v[8];
        #pragma unroll
        for (int u = 0; u < 8; ++u)
            v[u] = wstg[(r0 + rb + u) * SSTR + colL];
        #pragma unroll
        for (int u = 0; u < 8; ++u) {
            int r = rb + u;
            if (r > 0 && (m16 & (1u << r))) {
                if (cur >= 0)
                    atomicAdd(&dst[(size_t)cur * dstride + chbase + colL], acc);
                acc = 0.0f;
                cur = wcol[r0 + r];
            }
            acc += v[u];
        }
    }
    if (cur >= 0)
        atomicAdd(&dst[(size_t)cur * dstride + chbase + colL], acc);
}

__global__ __launch_bounds__(BLK, 4) void edge_hidden_reduce(
        const int4* __restrict__ rec, const float* __restrict__ eattr,
        const float* __restrict__ emb_port, const float* __restrict__ emb_flags,
        const float* __restrict__ W1, const float* __restrict__ b1,
        float* __restrict__ hsum, float* __restrict__ lsum, int base, int E) {
    __shared__ float stg[BLK * SSTR];
    __shared__ int col_sh[BLK];

    int tid = threadIdx.x;
    int lane = tid & 63;
    int wv = tid >> 6;
    int idx = base + blockIdx.x * BLK + tid;
    bool valid = idx < E;

    float* wstg = stg + wv * 64 * SSTR;
    int* wcol = col_sh + wv * 64;

    // ---- gather ea[34] into registers ----
    float ea[IN_DIM];
    #pragma unroll
    for (int k = 0; k < IN_DIM; ++k) ea[k] = 0.0f;
    int colv = -1;
    if (valid) {
        int4 r = rec[idx];
        int eid = r.x;
        unsigned pf = (unsigned)r.w;
        colv = r.z;
        const float4* ap = (const float4*)(eattr + (size_t)eid * 16);
        float4 a0 = ap[0], a1 = ap[1], a2 = ap[2], a3 = ap[3];
        ea[0]=a0.x; ea[1]=a0.y; ea[2]=a0.z; ea[3]=a0.w;
        ea[4]=a1.x; ea[5]=a1.y; ea[6]=a1.z; ea[7]=a1.w;
        ea[8]=a2.x; ea[9]=a2.y; ea[10]=a2.z; ea[11]=a2.w;
        ea[12]=a3.x; ea[13]=a3.y; ea[14]=a3.z; ea[15]=a3.w;
        int p = (int)(pf & 0xFFFFu);
        int f = (int)(pf >> 16);
        const float4* pp = (const float4*)(emb_port + (size_t)p * 16);
        float4 p0 = pp[0], p1 = pp[1], p2 = pp[2], p3 = pp[3];
        ea[16]=p0.x; ea[17]=p0.y; ea[18]=p0.z; ea[19]=p0.w;
        ea[20]=p1.x; ea[21]=p1.y; ea[22]=p1.z; ea[23]=p1.w;
        ea[24]=p2.x; ea[25]=p2.y; ea[26]=p2.z; ea[27]=p2.w;
        ea[28]=p3.x; ea[29]=p3.y; ea[30]=p3.z; ea[31]=p3.w;
        float2 fl = *(const float2*)(emb_flags + (size_t)f * 2);
        ea[32]=fl.x; ea[33]=fl.y;
    }
    wcol[lane] = colv;

    // segment-boundary mask (wave-uniform, lives in SGPRs)
    int prevcol = __shfl_up(colv, 1);
    unsigned long long bmask = __ballot(lane > 0 && colv != prevcol);

    // ---- passes 0,1: lsum channels 0-15 and 16-31 ----
    #pragma unroll
    for (int p = 0; p < 2; ++p) {
        #pragma unroll
        for (int j = 0; j < 16; ++j)
            wstg[lane * SSTR + j] = ea[p * 16 + j];
        WAVE_FENCE();
        strip_reduce16(wstg, wcol, lane, bmask, lsum, IN_DIM, p * 16);
        WAVE_FENCE();
    }

    // ---- pass 2: lsum channels 32,33 (2-col strip: 32 pairs x 2 rows) ----
    wstg[lane * SSTR + 0] = ea[32];
    wstg[lane * SSTR + 1] = ea[33];
    WAVE_FENCE();
    {
        int colL = lane & 1;
        int r0 = (lane >> 1) * 2;
        int c0 = wcol[r0], c1 = wcol[r0 + 1];
        float v0 = wstg[r0 * SSTR + colL];
        float v1 = wstg[(r0 + 1) * SSTR + colL];
        if (c0 == c1) {
            if (c0 >= 0)
                atomicAdd(&lsum[(size_t)c0 * IN_DIM + 32 + colL], v0 + v1);
        } else {
            if (c0 >= 0)
                atomicAdd(&lsum[(size_t)c0 * IN_DIM + 32 + colL], v0);
            if (c1 >= 0)
                atomicAdd(&lsum[(size_t)c1 * IN_DIM + 32 + colL], v1);
        }
    }
    WAVE_FENCE();

    // ---- h quarters: h[16] = relu(ea @ W1[:, q*16:+16] + b1) -> hsum ----
    #pragma unroll 1
    for (int q = 0; q < 4; ++q) {
        const float* w1q = W1 + q * 16;
        float h[16];
        #pragma unroll
        for (int j = 0; j < 16; ++j) h[j] = b1[q * 16 + j];
        #pragma unroll
        for (int k = 0; k < IN_DIM; ++k) {
            float v = ea[k];
            #pragma unroll
            for (int j = 0; j < 16; ++j)
                h[j] = fmaf(v, w1q[k * HID + j], h[j]);
        }
        #pragma unroll
        for (int j = 0; j < 16; ++j)
            wstg[lane * SSTR + j] = fmaxf(h[j], 0.0f);
        WAVE_FENCE();
        strip_reduce16(wstg, wcol, lane, bmask, hsum, HID, q * 16);
        WAVE_FENCE();
    }
}

// node_mlp (round-11 proven, -65us): v_readlane broadcasts (VALU pipe,
// zero DS ops) + NPW=4 nodes/wave with W1/W2 columns in registers.
__global__ __launch_bounds__(256) void node_mlp(
        const float* __restrict__ lsum, const float* __restrict__ hsum,
        const int* __restrict__ hist,
        const float* __restrict__ W1, const float* __restrict__ b1,
        const float* __restrict__ W2, const float* __restrict__ b2,
        float* __restrict__ s, __half* __restrict__ x1, int N) {
    int wid = (blockIdx.x * blockDim.x + threadIdx.x) >> 6;
    int lane = threadIdx.x & 63;
    int n0 = wid * NPW;
    if (n0 >= N) return;

    float w1r[IN_DIM];
    #pragma unroll
    for (int k = 0; k < IN_DIM; ++k) w1r[k] = W1[k * HID + lane];
    float w2r[HID];
    #pragma unroll
    for (int k = 0; k < HID; ++k) w2r[k] = W2[k * HID + lane];
    float b1v = b1[lane];
    float b2v = b2[lane];

    int n1 = min(n0 + NPW, N);
    #pragma unroll 1
    for (int n = n0; n < n1; ++n) {
        int c = hist[n];
        float invc = 1.0f / fmaxf((float)c, 1.0f);
        float lv = (lane < IN_DIM) ? lsum[(size_t)n * IN_DIM + lane] * invc : 0.0f;

        float h0 = b1v, h1 = 0.0f;
        #pragma unroll
        for (int k = 0; k < IN_DIM; k += 2) {
            h0 = fmaf(rl(lv, k),     w1r[k],     h0);
            h1 = fmaf(rl(lv, k + 1), w1r[k + 1], h1);
        }
        float hs = fmaxf(h0 + h1, 0.0f) + hsum[(size_t)n * HID + lane];

        float degf = (float)(c + 1);
        float invdeg = 1.0f / degf;
        float o0 = degf * b2v, o1 = 0.0f;
        #pragma unroll
        for (int k = 0; k < HID; k += 2) {
            o0 = fmaf(rl(hs, k),     w2r[k],     o0);
            o1 = fmaf(rl(hs, k + 1), w2r[k + 1], o1);
        }
        float o = o0 + o1;
        s[(size_t)n * HID + lane] = o;
        x1[(size_t)n * HID + lane] = __float2half(o * invdeg);
    }
}

// Wave per node, fully-batched clamped gather; x is FP16 (128B rows),
// fp32 accumulation. src ids come from rec[].y (4B at stride 16,
// wave-uniform sequential broadcast -- round-4-proven pattern).
__global__ __launch_bounds__(256) void gather_layer(
        const int* __restrict__ offs, const int* __restrict__ hist,
        const int4* __restrict__ rec, const __half* __restrict__ x,
        const float* __restrict__ s, __half* __restrict__ xn, int N) {
    int wid = (blockIdx.x * blockDim.x + threadIdx.x) >> 6;
    int lane = threadIdx.x & 63;
    if (wid >= N) return;
    int off = offs[wid], d = hist[wid];
    float acc = __half2float(x[(size_t)wid * HID + lane])
              + s[(size_t)wid * HID + lane];
    #pragma unroll 1
    for (int b = 0; b < d; b += 16) {
        int lim = d - b;                       // > 0
        int r[16];
        #pragma unroll
        for (int u = 0; u < 16; ++u)
            r[u] = rec[off + b + ((u < lim) ? u : (lim - 1))].y;
        __half v[16];
        #pragma unroll
        for (int u = 0; u < 16; ++u)
            v[u] = x[(size_t)r[u] * HID + lane];
        #pragma unroll
        for (int u = 0; u < 16; ++u)
            if (u < lim) acc += __half2float(v[u]);
    }
    xn[(size_t)wid * HID + lane] = __float2half(acc / (float)(d + 1));
}

// Wave per 64-node chunk; batch[] is sorted so flushes are rare.
__global__ __launch_bounds__(256) void pool_pass(
        const __half* __restrict__ x, const int* __restrict__ batch,
        float* __restrict__ psum, unsigned* __restrict__ pmax,
        float* __restrict__ pcnt, int N) {
    const int CHUNK = 64;
    int wid = (blockIdx.x * blockDim.x + threadIdx.x) >> 6;
    int lane = threadIdx.x & 63;
    int n0 = wid * CHUNK;
    if (n0 >= N) return;
    int n1 = min(n0 + CHUNK, N);
    int gcur = batch[n0];
    float sum = 0.0f, mx = -3.402823e38f;
    int cnt = 0;
    for (int n = n0; n < n1; ++n) {
        int g = batch[n];
        if (g != gcur) {
            atomicAdd(&psum[gcur * HID + lane], sum);
            atomicMax(&pmax[gcur * HID + lane], enc_f(mx));
            if (lane == 0) atomicAdd(&pcnt[gcur], (float)cnt);
            gcur = g; sum = 0.0f; mx = -3.402823e38f; cnt = 0;
        }
        float v = __half2float(x[(size_t)n * HID + lane]);
        sum += v;
        mx = fmaxf(mx, v);
        ++cnt;
    }
    atomicAdd(&psum[gcur * HID + lane], sum);
    atomicMax(&pmax[gcur * HID + lane], enc_f(mx));
    if (lane == 0) atomicAdd(&pcnt[gcur], (float)cnt);
}

__global__ __launch_bounds__(64) void classifier_pass(
        const float* __restrict__ psum, const unsigned* __restrict__ pmax,
        const float* __restrict__ pcnt,
        const float* __restrict__ CW1, const float* __restrict__ Cb1,
        const float* __restrict__ CW2, const float* __restrict__ Cb2,
        float* __restrict__ out) {
    int g = blockIdx.x, j = threadIdx.x;
    __shared__ float pooled[2 * HID];
    __shared__ float hsh[HID];
    float gc = fmaxf(pcnt[g], 1.0f);
    pooled[j] = psum[g * HID + j] / gc;
    pooled[HID + j] = dec_f(pmax[g * HID + j]);
    __syncthreads();
    float acc = Cb1[j];
    #pragma unroll 8
    for (int k = 0; k < 2 * HID; ++k) acc = fmaf(pooled[k], CW1[k * HID + j], acc);
    hsh[j] = fmaxf(acc, 0.0f);
    __syncthreads();
    if (j < NCLS) {
        float o = Cb2[j];
        #pragma unroll 8
        for (int k = 0; k < HID; ++k) o = fmaf(hsh[k], CW2[k * NCLS + j], o);
        out[g * NCLS + j] = o;
    }
}

// ---------- launch ----------

extern "C" void kernel_launch(void* const* d_in, const int* in_sizes, int n_in,
                              void* d_out, int out_size, void* d_ws, size_t ws_size,
                              hipStream_t stream) {
    const int*   ei        = (const int*)d_in[0];
    const int*   ports     = (const int*)d_in[1];
    const int*   flags     = (const int*)d_in[2];
    const float* eattr     = (const float*)d_in[3];
    const int*   batch     = (const int*)d_in[4];
    const float* emb_port  = (const float*)d_in[5];
    const float* emb_flags = (const float*)d_in[6];
    const float* W1  = (const float*)d_in[7];
    const float* b1  = (const float*)d_in[8];
    const float* W2  = (const float*)d_in[9];
    const float* b2  = (const float*)d_in[10];
    const float* CW1 = (const float*)d_in[11];
    const float* Cb1 = (const float*)d_in[12];
    const float* CW2 = (const float*)d_in[13];
    const float* Cb2 = (const float*)d_in[14];
    float* outp = (float*)d_out;

    const int E = in_sizes[0] / 2;
    const int N = in_sizes[4];
    const int B = out_size / NCLS;
    const int NB = (N + 255) / 256;     // scan blocks (must be <= 512)

    // ---- workspace layout (~106 MB; proven-safe budget >= 142 MB) ----
    char* w = (char*)d_ws;
    __half*   xA   = (__half*)w;  w += (size_t)N * HID * 2;
    __half*   xB   = (__half*)w;  w += (size_t)N * HID * 2;
    float*    s    = (float*)w;   w += (size_t)N * HID * 4;
    int4*     rec  = (int4*)w;    w += (size_t)E * 16;     // packed sorted records
    int*      offs = (int*)w;     w += (size_t)N * 4;
    int*      cursor = (int*)w;   w += (size_t)N * 4;
    int*      loc  = (int*)w;     w += (size_t)N * 4;
    int*      part = (int*)w;     w += 512 * 4;
    // zero region (single memset): hist, hsum, lsum, psum, pmax, pcnt
    char* zero_base = w;
    int*      hist = (int*)w;     w += (size_t)N * 4;
    float*    hsum = (float*)w;   w += (size_t)N * HID * 4;
    float*    lsum = (float*)w;   w += (size_t)N * IN_DIM * 4;
    float*    psum = (float*)w;   w += (size_t)B * HID * 4;
    unsigned* pmax = (unsigned*)w; w += (size_t)B * HID * 4;
    float*    pcnt = (float*)w;   w += (size_t)B * 4;
    size_t zero_bytes = (size_t)(w - zero_base);

    hipMemsetAsync(zero_base, 0, zero_bytes, stream);

    // CSR build + bucket sort by col (single 16B record per edge)
    hist_pass<<<(E + 255) / 256, 256, 0, stream>>>(ei, hist, E);
    scan1<<<NB, 256, 0, stream>>>(hist, loc, part, N);
    scan2<<<1, 512, 0, stream>>>(part, NB);
    scan3<<<NB, 256, 0, stream>>>(loc, part, offs, cursor, N);
    sort_pass<<<(E + 255) / 256, 256, 0, stream>>>(
        ei, ports, flags, cursor, rec, E);

    // edge hidden-layer + segmented reduction -> hsum, lsum
    // (two half-E dispatches: rocprof top-5 visibility; atomics make the
    //  split boundary correct)
    {
        int half = ((E / 2) + BLK - 1) / BLK * BLK;
        if (half > E) half = E;
        edge_hidden_reduce<<<(half + BLK - 1) / BLK, BLK, 0, stream>>>(
            rec, eattr, emb_port, emb_flags, W1, b1, hsum, lsum, 0, E);
        if (E > half)
            edge_hidden_reduce<<<(E - half + BLK - 1) / BLK, BLK, 0, stream>>>(
                rec, eattr, emb_port, emb_flags, W1, b1, hsum, lsum, half, E);
    }

    // per-node: self-loop hidden + W2 -> s, x1 (fp16); NPW nodes/wave
    node_mlp<<<(N + NPW * 4 - 1) / (NPW * 4), 256, 0, stream>>>(
        lsum, hsum, hist, W1, b1, W2, b2, s, xA, N);

    // layers 2 and 3 (fp16 state, fp32 accumulate)
    gather_layer<<<(N + 3) / 4, 256, 0, stream>>>(
        offs, hist, rec, xA, s, xB, N);
    gather_layer<<<(N + 3) / 4, 256, 0, stream>>>(
        offs, hist, rec, xB, s, xA, N);

    // pooling + classifier
    pool_pass<<<((N + 63) / 64 * 64 + 255) / 256, 256, 0, stream>>>(
        xA, batch, psum, pmax, pcnt, N);
    classifier_pass<<<B, 64, 0, stream>>>(psum, pmax, pcnt, CW1, Cb1, CW2, Cb2, outp);
}

// Round 13
// 715.595 us; speedup vs baseline: 1.0239x; 1.0239x over previous
//
#include <hip/hip_runtime.h>
#include <hip/hip_fp16.h>

#define HID 64
#define IN_DIM 34
#define NCLS 10
#define BLK 128
#define SSTR 17   // staging tile row stride (odd -> conflict-free col reads)
#define NPW 4     // node_mlp: nodes per wave (weight-reg amortization)
#define CPAD 16   // atomic counter padding: one counter per 64B line

// ---------- helpers ----------

__device__ __forceinline__ unsigned enc_f(float f) {
    unsigned u = __float_as_uint(f);
    return (u & 0x80000000u) ? ~u : (u | 0x80000000u);
}
__device__ __forceinline__ float dec_f(unsigned u) {
    return __uint_as_float((u & 0x80000000u) ? (u & 0x7FFFFFFFu) : ~u);
}
// readlane: broadcast on the VALU pipe (vs __shfl -> ds_bpermute on the
// DS pipe, which was node_mlp's wall: 9.8M DS ops chip-wide)
__device__ __forceinline__ float rl(float v, int k) {
    return __uint_as_float((unsigned)__builtin_amdgcn_readlane(
        (int)__float_as_uint(v), k));
}

// wave-local LDS fence: DS ops from one wave complete in order; lgkmcnt(0)
// guarantees all prior ds_writes are committed before later ds_reads issue.
#define WAVE_FENCE() do { \
    asm volatile("s_waitcnt lgkmcnt(0)" ::: "memory"); \
    __builtin_amdgcn_sched_barrier(0); \
} while (0)

// ---------- CSR build ----------
// ROUND 13: hist/cursor atomics PADDED to one counter per 64B line.
// Round-12 evidence: halving scattered-store volume left sort_pass at
// ~124us (VALUBusy 0.5%) -> the wall is the cursor atomicAdd returns.
// Packed counters put 16 per line; each line took ~256 cross-XCD
// atomics serialized with line-ownership migration. Padding cuts
// per-line contention 16x. scan1 emits a packed deg[] for downstream
// consumers so only the tiny scan reads go strided.

__global__ __launch_bounds__(256) void hist_pass(
        const int* __restrict__ ei, int* __restrict__ hist, int E) {
    int e = blockIdx.x * blockDim.x + threadIdx.x;
    if (e >= E) return;
    atomicAdd(&hist[(size_t)ei[E + e] * CPAD], 1);
}

__global__ __launch_bounds__(256) void scan1(
        const int* __restrict__ hist, int* __restrict__ loc,
        int* __restrict__ part, int* __restrict__ deg, int N) {
    __shared__ int sh[256];
    int tid = threadIdx.x;
    int i = blockIdx.x * 256 + tid;
    int v = (i < N) ? hist[(size_t)i * CPAD] : 0;
    sh[tid] = v;
    __syncthreads();
    for (int d = 1; d < 256; d <<= 1) {
        int t = (tid >= d) ? sh[tid - d] : 0;
        __syncthreads();
        sh[tid] += t;
        __syncthreads();
    }
    if (i < N) {
        loc[i] = sh[tid] - v;          // exclusive
        deg[i] = v;                    // packed copy for consumers
    }
    if (tid == 255) part[blockIdx.x] = sh[255];
}

__global__ __launch_bounds__(512) void scan2(int* __restrict__ part, int NB) {
    __shared__ int sh[512];
    int t = threadIdx.x;
    int v = (t < NB) ? part[t] : 0;
    sh[t] = v;
    __syncthreads();
    for (int d = 1; d < 512; d <<= 1) {
        int u = (t >= d) ? sh[t - d] : 0;
        __syncthreads();
        sh[t] += u;
        __syncthreads();
    }
    if (t < NB) part[t] = sh[t] - v;          // exclusive
}

__global__ __launch_bounds__(256) void scan3(
        const int* __restrict__ loc, const int* __restrict__ part,
        int* __restrict__ offs, int* __restrict__ cursor, int N) {
    int i = blockIdx.x * 256 + threadIdx.x;
    if (i >= N) return;
    int o = loc[i] + part[blockIdx.x];
    offs[i] = o;
    cursor[(size_t)i * CPAD] = o;
}

// bucket edges by col: 16B rec {eid, src, col, port|flag<<16} for ehr +
// contiguous 4B srcs[] for the gather layers (round-11 evidence: the
// extra scattered array costs no sort time, and contiguous src reads
// save the gathers ~10us each vs stride-16 rec.y).
__global__ __launch_bounds__(256) void sort_pass(
        const int* __restrict__ ei, const int* __restrict__ ports,
        const int* __restrict__ flags, int* __restrict__ cursor,
        int4* __restrict__ rec, int* __restrict__ srcs, int E) {
    int e = blockIdx.x * blockDim.x + threadIdx.x;
    if (e >= E) return;
    int c = ei[E + e];
    int src = ei[e];
    int pos = atomicAdd(&cursor[(size_t)c * CPAD], 1);
    int4 r;
    r.x = e;
    r.y = src;
    r.z = c;
    r.w = (int)((unsigned)ports[e] | ((unsigned)flags[e] << 16));
    rec[pos] = r;
    srcs[pos] = src;
}

// ---------- edge hidden-layer + wave-local segmented reduction ----------
// hsum[n] = sum_e relu(ea_e W1 + b1), lsum[n] = sum_e ea_e  (e: col==n).
// Two half-E dispatches (rocprof top-5 visibility; atomics make the split
// boundary correct). Ballot boundary mask in SGPRs (round 10).

__device__ __forceinline__ void strip_reduce16(
        const float* __restrict__ wstg, const int* __restrict__ wcol, int lane,
        unsigned long long bmask,
        float* __restrict__ dst, int dstride, int chbase) {
    // 4 strips of 16 rows; lane&15 owns one staged column.
    int colL = lane & 15;
    int r0 = (lane >> 4) * 16;
    unsigned m16 = (unsigned)(bmask >> r0) & 0xFFFFu;  // uniform per 16-lane group
    float acc = 0.0f;
    int cur = wcol[r0];
    #pragma unroll
    for (int rb = 0; rb < 16; rb += 8) {
        float v[8];
        #pragma unroll
        for (int u = 0; u < 8; ++u)
            v[u] = wstg[(r0 + rb + u) * SSTR + colL];
        #pragma unroll
        for (int u = 0; u < 8; ++u) {
            int r = rb + u;
            if (r > 0 && (m16 & (1u << r))) {
                if (cur >= 0)
                    atomicAdd(&dst[(size_t)cur * dstride + chbase + colL], acc);
                acc = 0.0f;
                cur = wcol[r0 + r];
            }
            acc += v[u];
        }
    }
    if (cur >= 0)
        atomicAdd(&dst[(size_t)cur * dstride + chbase + colL], acc);
}

__global__ __launch_bounds__(BLK, 4) void edge_hidden_reduce(
        const int4* __restrict__ rec, const float* __restrict__ eattr,
        const float* __restrict__ emb_port, const float* __restrict__ emb_flags,
        const float* __restrict__ W1, const float* __restrict__ b1,
        float* __restrict__ hsum, float* __restrict__ lsum, int base, int E) {
    __shared__ float stg[BLK * SSTR];
    __shared__ int col_sh[BLK];

    int tid = threadIdx.x;
    int lane = tid & 63;
    int wv = tid >> 6;
    int idx = base + blockIdx.x * BLK + tid;
    bool valid = idx < E;

    float* wstg = stg + wv * 64 * SSTR;
    int* wcol = col_sh + wv * 64;

    // ---- gather ea[34] into registers ----
    float ea[IN_DIM];
    #pragma unroll
    for (int k = 0; k < IN_DIM; ++k) ea[k] = 0.0f;
    int colv = -1;
    if (valid) {
        int4 r = rec[idx];
        int eid = r.x;
        unsigned pf = (unsigned)r.w;
        colv = r.z;
        const float4* ap = (const float4*)(eattr + (size_t)eid * 16);
        float4 a0 = ap[0], a1 = ap[1], a2 = ap[2], a3 = ap[3];
        ea[0]=a0.x; ea[1]=a0.y; ea[2]=a0.z; ea[3]=a0.w;
        ea[4]=a1.x; ea[5]=a1.y; ea[6]=a1.z; ea[7]=a1.w;
        ea[8]=a2.x; ea[9]=a2.y; ea[10]=a2.z; ea[11]=a2.w;
        ea[12]=a3.x; ea[13]=a3.y; ea[14]=a3.z; ea[15]=a3.w;
        int p = (int)(pf & 0xFFFFu);
        int f = (int)(pf >> 16);
        const float4* pp = (const float4*)(emb_port + (size_t)p * 16);
        float4 p0 = pp[0], p1 = pp[1], p2 = pp[2], p3 = pp[3];
        ea[16]=p0.x; ea[17]=p0.y; ea[18]=p0.z; ea[19]=p0.w;
        ea[20]=p1.x; ea[21]=p1.y; ea[22]=p1.z; ea[23]=p1.w;
        ea[24]=p2.x; ea[25]=p2.y; ea[26]=p2.z; ea[27]=p2.w;
        ea[28]=p3.x; ea[29]=p3.y; ea[30]=p3.z; ea[31]=p3.w;
        float2 fl = *(const float2*)(emb_flags + (size_t)f * 2);
        ea[32]=fl.x; ea[33]=fl.y;
    }
    wcol[lane] = colv;

    // segment-boundary mask (wave-uniform, lives in SGPRs)
    int prevcol = __shfl_up(colv, 1);
    unsigned long long bmask = __ballot(lane > 0 && colv != prevcol);

    // ---- passes 0,1: lsum channels 0-15 and 16-31 ----
    #pragma unroll
    for (int p = 0; p < 2; ++p) {
        #pragma unroll
        for (int j = 0; j < 16; ++j)
            wstg[lane * SSTR + j] = ea[p * 16 + j];
        WAVE_FENCE();
        strip_reduce16(wstg, wcol, lane, bmask, lsum, IN_DIM, p * 16);
        WAVE_FENCE();
    }

    // ---- pass 2: lsum channels 32,33 (2-col strip: 32 pairs x 2 rows) ----
    wstg[lane * SSTR + 0] = ea[32];
    wstg[lane * SSTR + 1] = ea[33];
    WAVE_FENCE();
    {
        int colL = lane & 1;
        int r0 = (lane >> 1) * 2;
        int c0 = wcol[r0], c1 = wcol[r0 + 1];
        float v0 = wstg[r0 * SSTR + colL];
        float v1 = wstg[(r0 + 1) * SSTR + colL];
        if (c0 == c1) {
            if (c0 >= 0)
                atomicAdd(&lsum[(size_t)c0 * IN_DIM + 32 + colL], v0 + v1);
        } else {
            if (c0 >= 0)
                atomicAdd(&lsum[(size_t)c0 * IN_DIM + 32 + colL], v0);
            if (c1 >= 0)
                atomicAdd(&lsum[(size_t)c1 * IN_DIM + 32 + colL], v1);
        }
    }
    WAVE_FENCE();

    // ---- h quarters: h[16] = relu(ea @ W1[:, q*16:+16] + b1) -> hsum ----
    #pragma unroll 1
    for (int q = 0; q < 4; ++q) {
        const float* w1q = W1 + q * 16;
        float h[16];
        #pragma unroll
        for (int j = 0; j < 16; ++j) h[j] = b1[q * 16 + j];
        #pragma unroll
        for (int k = 0; k < IN_DIM; ++k) {
            float v = ea[k];
            #pragma unroll
            for (int j = 0; j < 16; ++j)
                h[j] = fmaf(v, w1q[k * HID + j], h[j]);
        }
        #pragma unroll
        for (int j = 0; j < 16; ++j)
            wstg[lane * SSTR + j] = fmaxf(h[j], 0.0f);
        WAVE_FENCE();
        strip_reduce16(wstg, wcol, lane, bmask, hsum, HID, q * 16);
        WAVE_FENCE();
    }
}

// node_mlp (round-11 proven, -65us): v_readlane broadcasts (VALU pipe,
// zero DS ops) + NPW=4 nodes/wave with W1/W2 columns in registers.
__global__ __launch_bounds__(256) void node_mlp(
        const float* __restrict__ lsum, const float* __restrict__ hsum,
        const int* __restrict__ deg,
        const float* __restrict__ W1, const float* __restrict__ b1,
        const float* __restrict__ W2, const float* __restrict__ b2,
        float* __restrict__ s, __half* __restrict__ x1, int N) {
    int wid = (blockIdx.x * blockDim.x + threadIdx.x) >> 6;
    int lane = threadIdx.x & 63;
    int n0 = wid * NPW;
    if (n0 >= N) return;

    float w1r[IN_DIM];
    #pragma unroll
    for (int k = 0; k < IN_DIM; ++k) w1r[k] = W1[k * HID + lane];
    float w2r[HID];
    #pragma unroll
    for (int k = 0; k < HID; ++k) w2r[k] = W2[k * HID + lane];
    float b1v = b1[lane];
    float b2v = b2[lane];

    int n1 = min(n0 + NPW, N);
    #pragma unroll 1
    for (int n = n0; n < n1; ++n) {
        int c = deg[n];
        float invc = 1.0f / fmaxf((float)c, 1.0f);
        float lv = (lane < IN_DIM) ? lsum[(size_t)n * IN_DIM + lane] * invc : 0.0f;

        float h0 = b1v, h1 = 0.0f;
        #pragma unroll
        for (int k = 0; k < IN_DIM; k += 2) {
            h0 = fmaf(rl(lv, k),     w1r[k],     h0);
            h1 = fmaf(rl(lv, k + 1), w1r[k + 1], h1);
        }
        float hs = fmaxf(h0 + h1, 0.0f) + hsum[(size_t)n * HID + lane];

        float degf = (float)(c + 1);
        float invdeg = 1.0f / degf;
        float o0 = degf * b2v, o1 = 0.0f;
        #pragma unroll
        for (int k = 0; k < HID; k += 2) {
            o0 = fmaf(rl(hs, k),     w2r[k],     o0);
            o1 = fmaf(rl(hs, k + 1), w2r[k + 1], o1);
        }
        float o = o0 + o1;
        s[(size_t)n * HID + lane] = o;
        x1[(size_t)n * HID + lane] = __float2half(o * invdeg);
    }
}

// Wave per node, fully-batched clamped gather; x is FP16 (128B rows),
// fp32 accumulation; src ids from contiguous srcs[].
__global__ __launch_bounds__(256) void gather_layer(
        const int* __restrict__ offs, const int* __restrict__ deg,
        const int* __restrict__ srcs, const __half* __restrict__ x,
        const float* __restrict__ s, __half* __restrict__ xn, int N) {
    int wid = (blockIdx.x * blockDim.x + threadIdx.x) >> 6;
    int lane = threadIdx.x & 63;
    if (wid >= N) return;
    int off = offs[wid], d = deg[wid];
    float acc = __half2float(x[(size_t)wid * HID + lane])
              + s[(size_t)wid * HID + lane];
    #pragma unroll 1
    for (int b = 0; b < d; b += 16) {
        int lim = d - b;                       // > 0
        int r[16];
        #pragma unroll
        for (int u = 0; u < 16; ++u)
            r[u] = srcs[off + b + ((u < lim) ? u : (lim - 1))];
        __half v[16];
        #pragma unroll
        for (int u = 0; u < 16; ++u)
            v[u] = x[(size_t)r[u] * HID + lane];
        #pragma unroll
        for (int u = 0; u < 16; ++u)
            if (u < lim) acc += __half2float(v[u]);
    }
    xn[(size_t)wid * HID + lane] = __float2half(acc / (float)(d + 1));
}

// Wave per 64-node chunk; batch[] is sorted so flushes are rare.
__global__ __launch_bounds__(256) void pool_pass(
        const __half* __restrict__ x, const int* __restrict__ batch,
        float* __restrict__ psum, unsigned* __restrict__ pmax,
        float* __restrict__ pcnt, int N) {
    const int CHUNK = 64;
    int wid = (blockIdx.x * blockDim.x + threadIdx.x) >> 6;
    int lane = threadIdx.x & 63;
    int n0 = wid * CHUNK;
    if (n0 >= N) return;
    int n1 = min(n0 + CHUNK, N);
    int gcur = batch[n0];
    float sum = 0.0f, mx = -3.402823e38f;
    int cnt = 0;
    for (int n = n0; n < n1; ++n) {
        int g = batch[n];
        if (g != gcur) {
            atomicAdd(&psum[gcur * HID + lane], sum);
            atomicMax(&pmax[gcur * HID + lane], enc_f(mx));
            if (lane == 0) atomicAdd(&pcnt[gcur], (float)cnt);
            gcur = g; sum = 0.0f; mx = -3.402823e38f; cnt = 0;
        }
        float v = __half2float(x[(size_t)n * HID + lane]);
        sum += v;
        mx = fmaxf(mx, v);
        ++cnt;
    }
    atomicAdd(&psum[gcur * HID + lane], sum);
    atomicMax(&pmax[gcur * HID + lane], enc_f(mx));
    if (lane == 0) atomicAdd(&pcnt[gcur], (float)cnt);
}

__global__ __launch_bounds__(64) void classifier_pass(
        const float* __restrict__ psum, const unsigned* __restrict__ pmax,
        const float* __restrict__ pcnt,
        const float* __restrict__ CW1, const float* __restrict__ Cb1,
        const float* __restrict__ CW2, const float* __restrict__ Cb2,
        float* __restrict__ out) {
    int g = blockIdx.x, j = threadIdx.x;
    __shared__ float pooled[2 * HID];
    __shared__ float hsh[HID];
    float gc = fmaxf(pcnt[g], 1.0f);
    pooled[j] = psum[g * HID + j] / gc;
    pooled[HID + j] = dec_f(pmax[g * HID + j]);
    __syncthreads();
    float acc = Cb1[j];
    #pragma unroll 8
    for (int k = 0; k < 2 * HID; ++k) acc = fmaf(pooled[k], CW1[k * HID + j], acc);
    hsh[j] = fmaxf(acc, 0.0f);
    __syncthreads();
    if (j < NCLS) {
        float o = Cb2[j];
        #pragma unroll 8
        for (int k = 0; k < HID; ++k) o = fmaf(hsh[k], CW2[k * NCLS + j], o);
        out[g * NCLS + j] = o;
    }
}

// ---------- launch ----------

extern "C" void kernel_launch(void* const* d_in, const int* in_sizes, int n_in,
                              void* d_out, int out_size, void* d_ws, size_t ws_size,
                              hipStream_t stream) {
    const int*   ei        = (const int*)d_in[0];
    const int*   ports     = (const int*)d_in[1];
    const int*   flags     = (const int*)d_in[2];
    const float* eattr     = (const float*)d_in[3];
    const int*   batch     = (const int*)d_in[4];
    const float* emb_port  = (const float*)d_in[5];
    const float* emb_flags = (const float*)d_in[6];
    const float* W1  = (const float*)d_in[7];
    const float* b1  = (const float*)d_in[8];
    const float* W2  = (const float*)d_in[9];
    const float* b2  = (const float*)d_in[10];
    const float* CW1 = (const float*)d_in[11];
    const float* Cb1 = (const float*)d_in[12];
    const float* CW2 = (const float*)d_in[13];
    const float* Cb2 = (const float*)d_in[14];
    float* outp = (float*)d_out;

    const int E = in_sizes[0] / 2;
    const int N = in_sizes[4];
    const int B = out_size / NCLS;
    const int NB = (N + 255) / 256;     // scan blocks (must be <= 512)

    // ---- workspace layout (~137 MB; proven-safe budget >= 142 MB) ----
    char* w = (char*)d_ws;
    __half*   xA   = (__half*)w;  w += (size_t)N * HID * 2;
    __half*   xB   = (__half*)w;  w += (size_t)N * HID * 2;
    float*    s    = (float*)w;   w += (size_t)N * HID * 4;
    int4*     rec  = (int4*)w;    w += (size_t)E * 16;     // packed sorted records
    int*      srcs = (int*)w;     w += (size_t)E * 4;      // contiguous src ids
    int*      offs = (int*)w;     w += (size_t)N * 4;
    int*      cursor = (int*)w;   w += (size_t)N * CPAD * 4; // PADDED (1/line)
    int*      loc  = (int*)w;     w += (size_t)N * 4;
    int*      deg  = (int*)w;     w += (size_t)N * 4;      // packed degree copy
    int*      part = (int*)w;     w += 512 * 4;
    // zero region (single memset): hist(padded), hsum, lsum, psum, pmax, pcnt
    char* zero_base = w;
    int*      hist = (int*)w;     w += (size_t)N * CPAD * 4; // PADDED (1/line)
    float*    hsum = (float*)w;   w += (size_t)N * HID * 4;
    float*    lsum = (float*)w;   w += (size_t)N * IN_DIM * 4;
    float*    psum = (float*)w;   w += (size_t)B * HID * 4;
    unsigned* pmax = (unsigned*)w; w += (size_t)B * HID * 4;
    float*    pcnt = (float*)w;   w += (size_t)B * 4;
    size_t zero_bytes = (size_t)(w - zero_base);

    hipMemsetAsync(zero_base, 0, zero_bytes, stream);

    // CSR build + bucket sort by col (padded atomic counters)
    hist_pass<<<(E + 255) / 256, 256, 0, stream>>>(ei, hist, E);
    scan1<<<NB, 256, 0, stream>>>(hist, loc, part, deg, N);
    scan2<<<1, 512, 0, stream>>>(part, NB);
    scan3<<<NB, 256, 0, stream>>>(loc, part, offs, cursor, N);
    sort_pass<<<(E + 255) / 256, 256, 0, stream>>>(
        ei, ports, flags, cursor, rec, srcs, E);

    // edge hidden-layer + segmented reduction -> hsum, lsum
    // (two half-E dispatches: rocprof top-5 visibility; atomics make the
    //  split boundary correct)
    {
        int half = ((E / 2) + BLK - 1) / BLK * BLK;
        if (half > E) half = E;
        edge_hidden_reduce<<<(half + BLK - 1) / BLK, BLK, 0, stream>>>(
            rec, eattr, emb_port, emb_flags, W1, b1, hsum, lsum, 0, E);
        if (E > half)
            edge_hidden_reduce<<<(E - half + BLK - 1) / BLK, BLK, 0, stream>>>(
                rec, eattr, emb_port, emb_flags, W1, b1, hsum, lsum, half, E);
    }

    // per-node: self-loop hidden + W2 -> s, x1 (fp16); NPW nodes/wave
    node_mlp<<<(N + NPW * 4 - 1) / (NPW * 4), 256, 0, stream>>>(
        lsum, hsum, deg, W1, b1, W2, b2, s, xA, N);

    // layers 2 and 3 (fp16 state, fp32 accumulate)
    gather_layer<<<(N + 3) / 4, 256, 0, stream>>>(
        offs, deg, srcs, xA, s, xB, N);
    gather_layer<<<(N + 3) / 4, 256, 0, stream>>>(
        offs, deg, srcs, xB, s, xA, N);

    // pooling + classifier
    pool_pass<<<((N + 63) / 64 * 64 + 255) / 256, 256, 0, stream>>>(
        xA, batch, psum, pmax, pcnt, N);
    classifier_pass<<<B, 64, 0, stream>>>(psum, pmax, pcnt, CW1, Cb1, CW2, Cb2, outp);
}

// Round 14
// 679.854 us; speedup vs baseline: 1.0778x; 1.0526x over previous
//
#include <hip/hip_runtime.h>
#include <hip/hip_fp16.h>

#define HID 64
#define IN_DIM 34
#define NCLS 10
#define BLK 128
#define SSTR 17   // staging tile row stride (odd -> conflict-free col reads)
#define NPW 4     // node_mlp: nodes per wave (weight-reg amortization)
#define CPAD 16   // atomic counter padding: one counter per 64B line

// ---------- helpers ----------

__device__ __forceinline__ unsigned enc_f(float f) {
    unsigned u = __float_as_uint(f);
    return (u & 0x80000000u) ? ~u : (u | 0x80000000u);
}
__device__ __forceinline__ float dec_f(unsigned u) {
    return __uint_as_float((u & 0x80000000u) ? (u & 0x7FFFFFFFu) : ~u);
}
// readlane: broadcast on the VALU pipe (vs __shfl -> ds_bpermute on the
// DS pipe, which was node_mlp's wall: 9.8M DS ops chip-wide)
__device__ __forceinline__ float rl(float v, int k) {
    return __uint_as_float((unsigned)__builtin_amdgcn_readlane(
        (int)__float_as_uint(v), k));
}

// wave-local LDS fence: DS ops from one wave complete in order; lgkmcnt(0)
// guarantees all prior ds_writes are committed before later ds_reads issue.
#define WAVE_FENCE() do { \
    asm volatile("s_waitcnt lgkmcnt(0)" ::: "memory"); \
    __builtin_amdgcn_sched_barrier(0); \
} while (0)

// ---------- CSR build ----------
// ROUND 14: ONE atomic pass instead of two. Rounds 11-13 isolated
// sort_pass's wall to the device-scope atomicAdd itself (write-volume,
// payload-size, and counter-padding changes all null; VALUBusy 0.5%):
// with non-coherent per-XCD L2s every atomic executes at the memory-side
// coherence point, ~100us per 1.6M-op pass -- and hist_pass pays the
// SAME wall. Fix: hist_pass captures its atomicAdd return (that return
// IS the edge's rank within its col) into rank[e] (coalesced store);
// sort_pass becomes ATOMIC-FREE: pos = offs[col] + rank[e]. cursor[]
// deleted.

__global__ __launch_bounds__(256) void hist_pass(
        const int* __restrict__ ei, int* __restrict__ hist,
        int* __restrict__ rank, int E) {
    int e = blockIdx.x * blockDim.x + threadIdx.x;
    if (e >= E) return;
    rank[e] = atomicAdd(&hist[(size_t)ei[E + e] * CPAD], 1);
}

__global__ __launch_bounds__(256) void scan1(
        const int* __restrict__ hist, int* __restrict__ loc,
        int* __restrict__ part, int* __restrict__ deg, int N) {
    __shared__ int sh[256];
    int tid = threadIdx.x;
    int i = blockIdx.x * 256 + tid;
    int v = (i < N) ? hist[(size_t)i * CPAD] : 0;
    sh[tid] = v;
    __syncthreads();
    for (int d = 1; d < 256; d <<= 1) {
        int t = (tid >= d) ? sh[tid - d] : 0;
        __syncthreads();
        sh[tid] += t;
        __syncthreads();
    }
    if (i < N) {
        loc[i] = sh[tid] - v;          // exclusive
        deg[i] = v;                    // packed copy for consumers
    }
    if (tid == 255) part[blockIdx.x] = sh[255];
}

__global__ __launch_bounds__(512) void scan2(int* __restrict__ part, int NB) {
    __shared__ int sh[512];
    int t = threadIdx.x;
    int v = (t < NB) ? part[t] : 0;
    sh[t] = v;
    __syncthreads();
    for (int d = 1; d < 512; d <<= 1) {
        int u = (t >= d) ? sh[t - d] : 0;
        __syncthreads();
        sh[t] += u;
        __syncthreads();
    }
    if (t < NB) part[t] = sh[t] - v;          // exclusive
}

__global__ __launch_bounds__(256) void scan3(
        const int* __restrict__ loc, const int* __restrict__ part,
        int* __restrict__ offs, int N) {
    int i = blockIdx.x * 256 + threadIdx.x;
    if (i >= N) return;
    offs[i] = loc[i] + part[blockIdx.x];
}

// bucket edges by col -- ATOMIC-FREE: pos = offs[col] + rank[e].
// 16B rec {eid, src, col, port|flag<<16} for ehr + contiguous 4B srcs[]
// for the gather layers.
__global__ __launch_bounds__(256) void sort_pass(
        const int* __restrict__ ei, const int* __restrict__ ports,
        const int* __restrict__ flags, const int* __restrict__ offs,
        const int* __restrict__ rank,
        int4* __restrict__ rec, int* __restrict__ srcs, int E) {
    int e = blockIdx.x * blockDim.x + threadIdx.x;
    if (e >= E) return;
    int c = ei[E + e];
    int src = ei[e];
    int pos = offs[c] + rank[e];
    int4 r;
    r.x = e;
    r.y = src;
    r.z = c;
    r.w = (int)((unsigned)ports[e] | ((unsigned)flags[e] << 16));
    rec[pos] = r;
    srcs[pos] = src;
}

// ---------- edge hidden-layer + wave-local segmented reduction ----------
// hsum[n] = sum_e relu(ea_e W1 + b1), lsum[n] = sum_e ea_e  (e: col==n).
// Two half-E dispatches (rocprof top-5 visibility; atomics make the split
// boundary correct). Ballot boundary mask in SGPRs (round 10).

__device__ __forceinline__ void strip_reduce16(
        const float* __restrict__ wstg, const int* __restrict__ wcol, int lane,
        unsigned long long bmask,
        float* __restrict__ dst, int dstride, int chbase) {
    // 4 strips of 16 rows; lane&15 owns one staged column.
    int colL = lane & 15;
    int r0 = (lane >> 4) * 16;
    unsigned m16 = (unsigned)(bmask >> r0) & 0xFFFFu;  // uniform per 16-lane group
    float acc = 0.0f;
    int cur = wcol[r0];
    #pragma unroll
    for (int rb = 0; rb < 16; rb += 8) {
        float v[8];
        #pragma unroll
        for (int u = 0; u < 8; ++u)
            v[u] = wstg[(r0 + rb + u) * SSTR + colL];
        #pragma unroll
        for (int u = 0; u < 8; ++u) {
            int r = rb + u;
            if (r > 0 && (m16 & (1u << r))) {
                if (cur >= 0)
                    atomicAdd(&dst[(size_t)cur * dstride + chbase + colL], acc);
                acc = 0.0f;
                cur = wcol[r0 + r];
            }
            acc += v[u];
        }
    }
    if (cur >= 0)
        atomicAdd(&dst[(size_t)cur * dstride + chbase + colL], acc);
}

__global__ __launch_bounds__(BLK, 4) void edge_hidden_reduce(
        const int4* __restrict__ rec, const float* __restrict__ eattr,
        const float* __restrict__ emb_port, const float* __restrict__ emb_flags,
        const float* __restrict__ W1, const float* __restrict__ b1,
        float* __restrict__ hsum, float* __restrict__ lsum, int base, int E) {
    __shared__ float stg[BLK * SSTR];
    __shared__ int col_sh[BLK];

    int tid = threadIdx.x;
    int lane = tid & 63;
    int wv = tid >> 6;
    int idx = base + blockIdx.x * BLK + tid;
    bool valid = idx < E;

    float* wstg = stg + wv * 64 * SSTR;
    int* wcol = col_sh + wv * 64;

    // ---- gather ea[34] into registers ----
    float ea[IN_DIM];
    #pragma unroll
    for (int k = 0; k < IN_DIM; ++k) ea[k] = 0.0f;
    int colv = -1;
    if (valid) {
        int4 r = rec[idx];
        int eid = r.x;
        unsigned pf = (unsigned)r.w;
        colv = r.z;
        const float4* ap = (const float4*)(eattr + (size_t)eid * 16);
        float4 a0 = ap[0], a1 = ap[1], a2 = ap[2], a3 = ap[3];
        ea[0]=a0.x; ea[1]=a0.y; ea[2]=a0.z; ea[3]=a0.w;
        ea[4]=a1.x; ea[5]=a1.y; ea[6]=a1.z; ea[7]=a1.w;
        ea[8]=a2.x; ea[9]=a2.y; ea[10]=a2.z; ea[11]=a2.w;
        ea[12]=a3.x; ea[13]=a3.y; ea[14]=a3.z; ea[15]=a3.w;
        int p = (int)(pf & 0xFFFFu);
        int f = (int)(pf >> 16);
        const float4* pp = (const float4*)(emb_port + (size_t)p * 16);
        float4 p0 = pp[0], p1 = pp[1], p2 = pp[2], p3 = pp[3];
        ea[16]=p0.x; ea[17]=p0.y; ea[18]=p0.z; ea[19]=p0.w;
        ea[20]=p1.x; ea[21]=p1.y; ea[22]=p1.z; ea[23]=p1.w;
        ea[24]=p2.x; ea[25]=p2.y; ea[26]=p2.z; ea[27]=p2.w;
        ea[28]=p3.x; ea[29]=p3.y; ea[30]=p3.z; ea[31]=p3.w;
        float2 fl = *(const float2*)(emb_flags + (size_t)f * 2);
        ea[32]=fl.x; ea[33]=fl.y;
    }
    wcol[lane] = colv;

    // segment-boundary mask (wave-uniform, lives in SGPRs)
    int prevcol = __shfl_up(colv, 1);
    unsigned long long bmask = __ballot(lane > 0 && colv != prevcol);

    // ---- passes 0,1: lsum channels 0-15 and 16-31 ----
    #pragma unroll
    for (int p = 0; p < 2; ++p) {
        #pragma unroll
        for (int j = 0; j < 16; ++j)
            wstg[lane * SSTR + j] = ea[p * 16 + j];
        WAVE_FENCE();
        strip_reduce16(wstg, wcol, lane, bmask, lsum, IN_DIM, p * 16);
        WAVE_FENCE();
    }

    // ---- pass 2: lsum channels 32,33 (2-col strip: 32 pairs x 2 rows) ----
    wstg[lane * SSTR + 0] = ea[32];
    wstg[lane * SSTR + 1] = ea[33];
    WAVE_FENCE();
    {
        int colL = lane & 1;
        int r0 = (lane >> 1) * 2;
        int c0 = wcol[r0], c1 = wcol[r0 + 1];
        float v0 = wstg[r0 * SSTR + colL];
        float v1 = wstg[(r0 + 1) * SSTR + colL];
        if (c0 == c1) {
            if (c0 >= 0)
                atomicAdd(&lsum[(size_t)c0 * IN_DIM + 32 + colL], v0 + v1);
        } else {
            if (c0 >= 0)
                atomicAdd(&lsum[(size_t)c0 * IN_DIM + 32 + colL], v0);
            if (c1 >= 0)
                atomicAdd(&lsum[(size_t)c1 * IN_DIM + 32 + colL], v1);
        }
    }
    WAVE_FENCE();

    // ---- h quarters: h[16] = relu(ea @ W1[:, q*16:+16] + b1) -> hsum ----
    #pragma unroll 1
    for (int q = 0; q < 4; ++q) {
        const float* w1q = W1 + q * 16;
        float h[16];
        #pragma unroll
        for (int j = 0; j < 16; ++j) h[j] = b1[q * 16 + j];
        #pragma unroll
        for (int k = 0; k < IN_DIM; ++k) {
            float v = ea[k];
            #pragma unroll
            for (int j = 0; j < 16; ++j)
                h[j] = fmaf(v, w1q[k * HID + j], h[j]);
        }
        #pragma unroll
        for (int j = 0; j < 16; ++j)
            wstg[lane * SSTR + j] = fmaxf(h[j], 0.0f);
        WAVE_FENCE();
        strip_reduce16(wstg, wcol, lane, bmask, hsum, HID, q * 16);
        WAVE_FENCE();
    }
}

// node_mlp (round-11 proven, -65us): v_readlane broadcasts (VALU pipe,
// zero DS ops) + NPW=4 nodes/wave with W1/W2 columns in registers.
__global__ __launch_bounds__(256) void node_mlp(
        const float* __restrict__ lsum, const float* __restrict__ hsum,
        const int* __restrict__ deg,
        const float* __restrict__ W1, const float* __restrict__ b1,
        const float* __restrict__ W2, const float* __restrict__ b2,
        float* __restrict__ s, __half* __restrict__ x1, int N) {
    int wid = (blockIdx.x * blockDim.x + threadIdx.x) >> 6;
    int lane = threadIdx.x & 63;
    int n0 = wid * NPW;
    if (n0 >= N) return;

    float w1r[IN_DIM];
    #pragma unroll
    for (int k = 0; k < IN_DIM; ++k) w1r[k] = W1[k * HID + lane];
    float w2r[HID];
    #pragma unroll
    for (int k = 0; k < HID; ++k) w2r[k] = W2[k * HID + lane];
    float b1v = b1[lane];
    float b2v = b2[lane];

    int n1 = min(n0 + NPW, N);
    #pragma unroll 1
    for (int n = n0; n < n1; ++n) {
        int c = deg[n];
        float invc = 1.0f / fmaxf((float)c, 1.0f);
        float lv = (lane < IN_DIM) ? lsum[(size_t)n * IN_DIM + lane] * invc : 0.0f;

        float h0 = b1v, h1 = 0.0f;
        #pragma unroll
        for (int k = 0; k < IN_DIM; k += 2) {
            h0 = fmaf(rl(lv, k),     w1r[k],     h0);
            h1 = fmaf(rl(lv, k + 1), w1r[k + 1], h1);
        }
        float hs = fmaxf(h0 + h1, 0.0f) + hsum[(size_t)n * HID + lane];

        float degf = (float)(c + 1);
        float invdeg = 1.0f / degf;
        float o0 = degf * b2v, o1 = 0.0f;
        #pragma unroll
        for (int k = 0; k < HID; k += 2) {
            o0 = fmaf(rl(hs, k),     w2r[k],     o0);
            o1 = fmaf(rl(hs, k + 1), w2r[k + 1], o1);
        }
        float o = o0 + o1;
        s[(size_t)n * HID + lane] = o;
        x1[(size_t)n * HID + lane] = __float2half(o * invdeg);
    }
}

// Wave per node, fully-batched clamped gather; x is FP16 (128B rows),
// fp32 accumulation; src ids from contiguous srcs[].
__global__ __launch_bounds__(256) void gather_layer(
        const int* __restrict__ offs, const int* __restrict__ deg,
        const int* __restrict__ srcs, const __half* __restrict__ x,
        const float* __restrict__ s, __half* __restrict__ xn, int N) {
    int wid = (blockIdx.x * blockDim.x + threadIdx.x) >> 6;
    int lane = threadIdx.x & 63;
    if (wid >= N) return;
    int off = offs[wid], d = deg[wid];
    float acc = __half2float(x[(size_t)wid * HID + lane])
              + s[(size_t)wid * HID + lane];
    #pragma unroll 1
    for (int b = 0; b < d; b += 16) {
        int lim = d - b;                       // > 0
        int r[16];
        #pragma unroll
        for (int u = 0; u < 16; ++u)
            r[u] = srcs[off + b + ((u < lim) ? u : (lim - 1))];
        __half v[16];
        #pragma unroll
        for (int u = 0; u < 16; ++u)
            v[u] = x[(size_t)r[u] * HID + lane];
        #pragma unroll
        for (int u = 0; u < 16; ++u)
            if (u < lim) acc += __half2float(v[u]);
    }
    xn[(size_t)wid * HID + lane] = __float2half(acc / (float)(d + 1));
}

// Wave per 64-node chunk; batch[] is sorted so flushes are rare.
__global__ __launch_bounds__(256) void pool_pass(
        const __half* __restrict__ x, const int* __restrict__ batch,
        float* __restrict__ psum, unsigned* __restrict__ pmax,
        float* __restrict__ pcnt, int N) {
    const int CHUNK = 64;
    int wid = (blockIdx.x * blockDim.x + threadIdx.x) >> 6;
    int lane = threadIdx.x & 63;
    int n0 = wid * CHUNK;
    if (n0 >= N) return;
    int n1 = min(n0 + CHUNK, N);
    int gcur = batch[n0];
    float sum = 0.0f, mx = -3.402823e38f;
    int cnt = 0;
    for (int n = n0; n < n1; ++n) {
        int g = batch[n];
        if (g != gcur) {
            atomicAdd(&psum[gcur * HID + lane], sum);
            atomicMax(&pmax[gcur * HID + lane], enc_f(mx));
            if (lane == 0) atomicAdd(&pcnt[gcur], (float)cnt);
            gcur = g; sum = 0.0f; mx = -3.402823e38f; cnt = 0;
        }
        float v = __half2float(x[(size_t)n * HID + lane]);
        sum += v;
        mx = fmaxf(mx, v);
        ++cnt;
    }
    atomicAdd(&psum[gcur * HID + lane], sum);
    atomicMax(&pmax[gcur * HID + lane], enc_f(mx));
    if (lane == 0) atomicAdd(&pcnt[gcur], (float)cnt);
}

__global__ __launch_bounds__(64) void classifier_pass(
        const float* __restrict__ psum, const unsigned* __restrict__ pmax,
        const float* __restrict__ pcnt,
        const float* __restrict__ CW1, const float* __restrict__ Cb1,
        const float* __restrict__ CW2, const float* __restrict__ Cb2,
        float* __restrict__ out) {
    int g = blockIdx.x, j = threadIdx.x;
    __shared__ float pooled[2 * HID];
    __shared__ float hsh[HID];
    float gc = fmaxf(pcnt[g], 1.0f);
    pooled[j] = psum[g * HID + j] / gc;
    pooled[HID + j] = dec_f(pmax[g * HID + j]);
    __syncthreads();
    float acc = Cb1[j];
    #pragma unroll 8
    for (int k = 0; k < 2 * HID; ++k) acc = fmaf(pooled[k], CW1[k * HID + j], acc);
    hsh[j] = fmaxf(acc, 0.0f);
    __syncthreads();
    if (j < NCLS) {
        float o = Cb2[j];
        #pragma unroll 8
        for (int k = 0; k < HID; ++k) o = fmaf(hsh[k], CW2[k * NCLS + j], o);
        out[g * NCLS + j] = o;
    }
}

// ---------- launch ----------

extern "C" void kernel_launch(void* const* d_in, const int* in_sizes, int n_in,
                              void* d_out, int out_size, void* d_ws, size_t ws_size,
                              hipStream_t stream) {
    const int*   ei        = (const int*)d_in[0];
    const int*   ports     = (const int*)d_in[1];
    const int*   flags     = (const int*)d_in[2];
    const float* eattr     = (const float*)d_in[3];
    const int*   batch     = (const int*)d_in[4];
    const float* emb_port  = (const float*)d_in[5];
    const float* emb_flags = (const float*)d_in[6];
    const float* W1  = (const float*)d_in[7];
    const float* b1  = (const float*)d_in[8];
    const float* W2  = (const float*)d_in[9];
    const float* b2  = (const float*)d_in[10];
    const float* CW1 = (const float*)d_in[11];
    const float* Cb1 = (const float*)d_in[12];
    const float* CW2 = (const float*)d_in[13];
    const float* Cb2 = (const float*)d_in[14];
    float* outp = (float*)d_out;

    const int E = in_sizes[0] / 2;
    const int N = in_sizes[4];
    const int B = out_size / NCLS;
    const int NB = (N + 255) / 256;     // scan blocks (must be <= 512)

    // ---- workspace layout (~137 MB; proven-safe budget >= 142 MB) ----
    char* w = (char*)d_ws;
    __half*   xA   = (__half*)w;  w += (size_t)N * HID * 2;
    __half*   xB   = (__half*)w;  w += (size_t)N * HID * 2;
    float*    s    = (float*)w;   w += (size_t)N * HID * 4;
    int4*     rec  = (int4*)w;    w += (size_t)E * 16;     // packed sorted records
    int*      srcs = (int*)w;     w += (size_t)E * 4;      // contiguous src ids
    int*      rank = (int*)w;     w += (size_t)E * 4;      // rank within col
    int*      offs = (int*)w;     w += (size_t)N * 4;
    int*      loc  = (int*)w;     w += (size_t)N * 4;
    int*      deg  = (int*)w;     w += (size_t)N * 4;      // packed degree copy
    int*      part = (int*)w;     w += 512 * 4;
    // zero region (single memset): hist(padded), hsum, lsum, psum, pmax, pcnt
    char* zero_base = w;
    int*      hist = (int*)w;     w += (size_t)N * CPAD * 4; // PADDED (1/line)
    float*    hsum = (float*)w;   w += (size_t)N * HID * 4;
    float*    lsum = (float*)w;   w += (size_t)N * IN_DIM * 4;
    float*    psum = (float*)w;   w += (size_t)B * HID * 4;
    unsigned* pmax = (unsigned*)w; w += (size_t)B * HID * 4;
    float*    pcnt = (float*)w;   w += (size_t)B * 4;
    size_t zero_bytes = (size_t)(w - zero_base);

    hipMemsetAsync(zero_base, 0, zero_bytes, stream);

    // CSR build: ONE atomic pass (hist captures rank); sort is atomic-free
    hist_pass<<<(E + 255) / 256, 256, 0, stream>>>(ei, hist, rank, E);
    scan1<<<NB, 256, 0, stream>>>(hist, loc, part, deg, N);
    scan2<<<1, 512, 0, stream>>>(part, NB);
    scan3<<<NB, 256, 0, stream>>>(loc, part, offs, N);
    sort_pass<<<(E + 255) / 256, 256, 0, stream>>>(
        ei, ports, flags, offs, rank, rec, srcs, E);

    // edge hidden-layer + segmented reduction -> hsum, lsum
    // (two half-E dispatches: rocprof top-5 visibility; atomics make the
    //  split boundary correct)
    {
        int half = ((E / 2) + BLK - 1) / BLK * BLK;
        if (half > E) half = E;
        edge_hidden_reduce<<<(half + BLK - 1) / BLK, BLK, 0, stream>>>(
            rec, eattr, emb_port, emb_flags, W1, b1, hsum, lsum, 0, E);
        if (E > half)
            edge_hidden_reduce<<<(E - half + BLK - 1) / BLK, BLK, 0, stream>>>(
                rec, eattr, emb_port, emb_flags, W1, b1, hsum, lsum, half, E);
    }

    // per-node: self-loop hidden + W2 -> s, x1 (fp16); NPW nodes/wave
    node_mlp<<<(N + NPW * 4 - 1) / (NPW * 4), 256, 0, stream>>>(
        lsum, hsum, deg, W1, b1, W2, b2, s, xA, N);

    // layers 2 and 3 (fp16 state, fp32 accumulate)
    gather_layer<<<(N + 3) / 4, 256, 0, stream>>>(
        offs, deg, srcs, xA, s, xB, N);
    gather_layer<<<(N + 3) / 4, 256, 0, stream>>>(
        offs, deg, srcs, xB, s, xA, N);

    // pooling + classifier
    pool_pass<<<((N + 63) / 64 * 64 + 255) / 256, 256, 0, stream>>>(
        xA, batch, psum, pmax, pcnt, N);
    classifier_pass<<<B, 64, 0, stream>>>(psum, pmax, pcnt, CW1, Cb1, CW2, Cb2, outp);
}

// Round 15
// 653.491 us; speedup vs baseline: 1.1213x; 1.0403x over previous
//
#include <hip/hip_runtime.h>
#include <hip/hip_fp16.h>

#define HID 64
#define IN_DIM 34
#define NCLS 10
#define BLK 128
#define SSTR 17   // staging tile row stride (odd -> conflict-free col reads)
#define NPW 4     // node_mlp: nodes per wave (weight-reg amortization)
#define CPAD 16   // atomic counter padding: one counter per 64B line

// ---------- helpers ----------

__device__ __forceinline__ unsigned enc_f(float f) {
    unsigned u = __float_as_uint(f);
    return (u & 0x80000000u) ? ~u : (u | 0x80000000u);
}
__device__ __forceinline__ float dec_f(unsigned u) {
    return __uint_as_float((u & 0x80000000u) ? (u & 0x7FFFFFFFu) : ~u);
}
// readlane: broadcast on the VALU pipe (vs __shfl -> ds_bpermute on the
// DS pipe, which was node_mlp's wall: 9.8M DS ops chip-wide)
__device__ __forceinline__ float rl(float v, int k) {
    return __uint_as_float((unsigned)__builtin_amdgcn_readlane(
        (int)__float_as_uint(v), k));
}

// wave-local LDS fence: DS ops from one wave complete in order; lgkmcnt(0)
// guarantees all prior ds_writes are committed before later ds_reads issue.
#define WAVE_FENCE() do { \
    asm volatile("s_waitcnt lgkmcnt(0)" ::: "memory"); \
    __builtin_amdgcn_sched_barrier(0); \
} while (0)

// ---------- CSR build ----------
// ONE atomic pass (round 14, -36us): hist_pass captures its atomicAdd
// return -- that return IS the edge's rank within its col -- into
// rank[e]; sort_pass is atomic-free: pos = offs[col] + rank[e].
// (Rounds 11-13 isolated the old sort wall to the device-scope atomic
// RMW itself: write-volume, payload, and padding changes were all null.)

__global__ __launch_bounds__(256) void hist_pass(
        const int* __restrict__ ei, int* __restrict__ hist,
        int* __restrict__ rank, int E) {
    int e = blockIdx.x * blockDim.x + threadIdx.x;
    if (e >= E) return;
    rank[e] = atomicAdd(&hist[(size_t)ei[E + e] * CPAD], 1);
}

__global__ __launch_bounds__(256) void scan1(
        const int* __restrict__ hist, int* __restrict__ loc,
        int* __restrict__ part, int* __restrict__ deg, int N) {
    __shared__ int sh[256];
    int tid = threadIdx.x;
    int i = blockIdx.x * 256 + tid;
    int v = (i < N) ? hist[(size_t)i * CPAD] : 0;
    sh[tid] = v;
    __syncthreads();
    for (int d = 1; d < 256; d <<= 1) {
        int t = (tid >= d) ? sh[tid - d] : 0;
        __syncthreads();
        sh[tid] += t;
        __syncthreads();
    }
    if (i < N) {
        loc[i] = sh[tid] - v;          // exclusive
        deg[i] = v;                    // packed copy for consumers
    }
    if (tid == 255) part[blockIdx.x] = sh[255];
}

__global__ __launch_bounds__(512) void scan2(int* __restrict__ part, int NB) {
    __shared__ int sh[512];
    int t = threadIdx.x;
    int v = (t < NB) ? part[t] : 0;
    sh[t] = v;
    __syncthreads();
    for (int d = 1; d < 512; d <<= 1) {
        int u = (t >= d) ? sh[t - d] : 0;
        __syncthreads();
        sh[t] += u;
        __syncthreads();
    }
    if (t < NB) part[t] = sh[t] - v;          // exclusive
}

__global__ __launch_bounds__(256) void scan3(
        const int* __restrict__ loc, const int* __restrict__ part,
        int* __restrict__ offs, int N) {
    int i = blockIdx.x * 256 + threadIdx.x;
    if (i >= N) return;
    offs[i] = loc[i] + part[blockIdx.x];
}

// bucket edges by col -- ATOMIC-FREE: pos = offs[col] + rank[e].
// 16B rec {eid, src, col, port|flag<<16} for ehr + contiguous 4B srcs[]
// for the gather layers.
__global__ __launch_bounds__(256) void sort_pass(
        const int* __restrict__ ei, const int* __restrict__ ports,
        const int* __restrict__ flags, const int* __restrict__ offs,
        const int* __restrict__ rank,
        int4* __restrict__ rec, int* __restrict__ srcs, int E) {
    int e = blockIdx.x * blockDim.x + threadIdx.x;
    if (e >= E) return;
    int c = ei[E + e];
    int src = ei[e];
    int pos = offs[c] + rank[e];
    int4 r;
    r.x = e;
    r.y = src;
    r.z = c;
    r.w = (int)((unsigned)ports[e] | ((unsigned)flags[e] << 16));
    rec[pos] = r;
    srcs[pos] = src;
}

// ---------- edge hidden-layer + wave-local segmented reduction ----------
// hsum[n] = sum_e relu(ea_e W1 + b1), lsum[n] = sum_e ea_e  (e: col==n).
// ROUND 15: merged back to a SINGLE full-E dispatch. The round-10 half-E
// split (rocprof visibility) cost ~48us: 6250 blocks vs ~4096 resident =
// 1.5 fills with ~25% drain tail, paid twice; full-E is 3 fills with an
// ~8% tail (measured: halves 107us x2 = 214 vs 166 single, round 9/14).
// The pipeline map is complete -- visibility rent no longer needed.

__device__ __forceinline__ void strip_reduce16(
        const float* __restrict__ wstg, const int* __restrict__ wcol, int lane,
        unsigned long long bmask,
        float* __restrict__ dst, int dstride, int chbase) {
    // 4 strips of 16 rows; lane&15 owns one staged column.
    int colL = lane & 15;
    int r0 = (lane >> 4) * 16;
    unsigned m16 = (unsigned)(bmask >> r0) & 0xFFFFu;  // uniform per 16-lane group
    float acc = 0.0f;
    int cur = wcol[r0];
    #pragma unroll
    for (int rb = 0; rb < 16; rb += 8) {
        float v[8];
        #pragma unroll
        for (int u = 0; u < 8; ++u)
            v[u] = wstg[(r0 + rb + u) * SSTR + colL];
        #pragma unroll
        for (int u = 0; u < 8; ++u) {
            int r = rb + u;
            if (r > 0 && (m16 & (1u << r))) {
                if (cur >= 0)
                    atomicAdd(&dst[(size_t)cur * dstride + chbase + colL], acc);
                acc = 0.0f;
                cur = wcol[r0 + r];
            }
            acc += v[u];
        }
    }
    if (cur >= 0)
        atomicAdd(&dst[(size_t)cur * dstride + chbase + colL], acc);
}

__global__ __launch_bounds__(BLK, 4) void edge_hidden_reduce(
        const int4* __restrict__ rec, const float* __restrict__ eattr,
        const float* __restrict__ emb_port, const float* __restrict__ emb_flags,
        const float* __restrict__ W1, const float* __restrict__ b1,
        float* __restrict__ hsum, float* __restrict__ lsum, int E) {
    __shared__ float stg[BLK * SSTR];
    __shared__ int col_sh[BLK];

    int tid = threadIdx.x;
    int lane = tid & 63;
    int wv = tid >> 6;
    int idx = blockIdx.x * BLK + tid;
    bool valid = idx < E;

    float* wstg = stg + wv * 64 * SSTR;
    int* wcol = col_sh + wv * 64;

    // ---- gather ea[34] into registers ----
    float ea[IN_DIM];
    #pragma unroll
    for (int k = 0; k < IN_DIM; ++k) ea[k] = 0.0f;
    int colv = -1;
    if (valid) {
        int4 r = rec[idx];
        int eid = r.x;
        unsigned pf = (unsigned)r.w;
        colv = r.z;
        const float4* ap = (const float4*)(eattr + (size_t)eid * 16);
        float4 a0 = ap[0], a1 = ap[1], a2 = ap[2], a3 = ap[3];
        ea[0]=a0.x; ea[1]=a0.y; ea[2]=a0.z; ea[3]=a0.w;
        ea[4]=a1.x; ea[5]=a1.y; ea[6]=a1.z; ea[7]=a1.w;
        ea[8]=a2.x; ea[9]=a2.y; ea[10]=a2.z; ea[11]=a2.w;
        ea[12]=a3.x; ea[13]=a3.y; ea[14]=a3.z; ea[15]=a3.w;
        int p = (int)(pf & 0xFFFFu);
        int f = (int)(pf >> 16);
        const float4* pp = (const float4*)(emb_port + (size_t)p * 16);
        float4 p0 = pp[0], p1 = pp[1], p2 = pp[2], p3 = pp[3];
        ea[16]=p0.x; ea[17]=p0.y; ea[18]=p0.z; ea[19]=p0.w;
        ea[20]=p1.x; ea[21]=p1.y; ea[22]=p1.z; ea[23]=p1.w;
        ea[24]=p2.x; ea[25]=p2.y; ea[26]=p2.z; ea[27]=p2.w;
        ea[28]=p3.x; ea[29]=p3.y; ea[30]=p3.z; ea[31]=p3.w;
        float2 fl = *(const float2*)(emb_flags + (size_t)f * 2);
        ea[32]=fl.x; ea[33]=fl.y;
    }
    wcol[lane] = colv;

    // segment-boundary mask (wave-uniform, lives in SGPRs)
    int prevcol = __shfl_up(colv, 1);
    unsigned long long bmask = __ballot(lane > 0 && colv != prevcol);

    // ---- passes 0,1: lsum channels 0-15 and 16-31 ----
    #pragma unroll
    for (int p = 0; p < 2; ++p) {
        #pragma unroll
        for (int j = 0; j < 16; ++j)
            wstg[lane * SSTR + j] = ea[p * 16 + j];
        WAVE_FENCE();
        strip_reduce16(wstg, wcol, lane, bmask, lsum, IN_DIM, p * 16);
        WAVE_FENCE();
    }

    // ---- pass 2: lsum channels 32,33 (2-col strip: 32 pairs x 2 rows) ----
    wstg[lane * SSTR + 0] = ea[32];
    wstg[lane * SSTR + 1] = ea[33];
    WAVE_FENCE();
    {
        int colL = lane & 1;
        int r0 = (lane >> 1) * 2;
        int c0 = wcol[r0], c1 = wcol[r0 + 1];
        float v0 = wstg[r0 * SSTR + colL];
        float v1 = wstg[(r0 + 1) * SSTR + colL];
        if (c0 == c1) {
            if (c0 >= 0)
                atomicAdd(&lsum[(size_t)c0 * IN_DIM + 32 + colL], v0 + v1);
        } else {
            if (c0 >= 0)
                atomicAdd(&lsum[(size_t)c0 * IN_DIM + 32 + colL], v0);
            if (c1 >= 0)
                atomicAdd(&lsum[(size_t)c1 * IN_DIM + 32 + colL], v1);
        }
    }
    WAVE_FENCE();

    // ---- h quarters: h[16] = relu(ea @ W1[:, q*16:+16] + b1) -> hsum ----
    #pragma unroll 1
    for (int q = 0; q < 4; ++q) {
        const float* w1q = W1 + q * 16;
        float h[16];
        #pragma unroll
        for (int j = 0; j < 16; ++j) h[j] = b1[q * 16 + j];
        #pragma unroll
        for (int k = 0; k < IN_DIM; ++k) {
            float v = ea[k];
            #pragma unroll
            for (int j = 0; j < 16; ++j)
                h[j] = fmaf(v, w1q[k * HID + j], h[j]);
        }
        #pragma unroll
        for (int j = 0; j < 16; ++j)
            wstg[lane * SSTR + j] = fmaxf(h[j], 0.0f);
        WAVE_FENCE();
        strip_reduce16(wstg, wcol, lane, bmask, hsum, HID, q * 16);
        WAVE_FENCE();
    }
}

// node_mlp (round-11 proven, -65us): v_readlane broadcasts (VALU pipe,
// zero DS ops) + NPW=4 nodes/wave with W1/W2 columns in registers.
__global__ __launch_bounds__(256) void node_mlp(
        const float* __restrict__ lsum, const float* __restrict__ hsum,
        const int* __restrict__ deg,
        const float* __restrict__ W1, const float* __restrict__ b1,
        const float* __restrict__ W2, const float* __restrict__ b2,
        float* __restrict__ s, __half* __restrict__ x1, int N) {
    int wid = (blockIdx.x * blockDim.x + threadIdx.x) >> 6;
    int lane = threadIdx.x & 63;
    int n0 = wid * NPW;
    if (n0 >= N) return;

    float w1r[IN_DIM];
    #pragma unroll
    for (int k = 0; k < IN_DIM; ++k) w1r[k] = W1[k * HID + lane];
    float w2r[HID];
    #pragma unroll
    for (int k = 0; k < HID; ++k) w2r[k] = W2[k * HID + lane];
    float b1v = b1[lane];
    float b2v = b2[lane];

    int n1 = min(n0 + NPW, N);
    #pragma unroll 1
    for (int n = n0; n < n1; ++n) {
        int c = deg[n];
        float invc = 1.0f / fmaxf((float)c, 1.0f);
        float lv = (lane < IN_DIM) ? lsum[(size_t)n * IN_DIM + lane] * invc : 0.0f;

        float h0 = b1v, h1 = 0.0f;
        #pragma unroll
        for (int k = 0; k < IN_DIM; k += 2) {
            h0 = fmaf(rl(lv, k),     w1r[k],     h0);
            h1 = fmaf(rl(lv, k + 1), w1r[k + 1], h1);
        }
        float hs = fmaxf(h0 + h1, 0.0f) + hsum[(size_t)n * HID + lane];

        float degf = (float)(c + 1);
        float invdeg = 1.0f / degf;
        float o0 = degf * b2v, o1 = 0.0f;
        #pragma unroll
        for (int k = 0; k < HID; k += 2) {
            o0 = fmaf(rl(hs, k),     w2r[k],     o0);
            o1 = fmaf(rl(hs, k + 1), w2r[k + 1], o1);
        }
        float o = o0 + o1;
        s[(size_t)n * HID + lane] = o;
        x1[(size_t)n * HID + lane] = __float2half(o * invdeg);
    }
}

// Wave per node, fully-batched clamped gather; x is FP16 (128B rows),
// fp32 accumulation; src ids from contiguous srcs[].
__global__ __launch_bounds__(256) void gather_layer(
        const int* __restrict__ offs, const int* __restrict__ deg,
        const int* __restrict__ srcs, const __half* __restrict__ x,
        const float* __restrict__ s, __half* __restrict__ xn, int N) {
    int wid = (blockIdx.x * blockDim.x + threadIdx.x) >> 6;
    int lane = threadIdx.x & 63;
    if (wid >= N) return;
    int off = offs[wid], d = deg[wid];
    float acc = __half2float(x[(size_t)wid * HID + lane])
              + s[(size_t)wid * HID + lane];
    #pragma unroll 1
    for (int b = 0; b < d; b += 16) {
        int lim = d - b;                       // > 0
        int r[16];
        #pragma unroll
        for (int u = 0; u < 16; ++u)
            r[u] = srcs[off + b + ((u < lim) ? u : (lim - 1))];
        __half v[16];
        #pragma unroll
        for (int u = 0; u < 16; ++u)
            v[u] = x[(size_t)r[u] * HID + lane];
        #pragma unroll
        for (int u = 0; u < 16; ++u)
            if (u < lim) acc += __half2float(v[u]);
    }
    xn[(size_t)wid * HID + lane] = __float2half(acc / (float)(d + 1));
}

// Wave per 64-node chunk; batch[] is sorted so flushes are rare.
__global__ __launch_bounds__(256) void pool_pass(
        const __half* __restrict__ x, const int* __restrict__ batch,
        float* __restrict__ psum, unsigned* __restrict__ pmax,
        float* __restrict__ pcnt, int N) {
    const int CHUNK = 64;
    int wid = (blockIdx.x * blockDim.x + threadIdx.x) >> 6;
    int lane = threadIdx.x & 63;
    int n0 = wid * CHUNK;
    if (n0 >= N) return;
    int n1 = min(n0 + CHUNK, N);
    int gcur = batch[n0];
    float sum = 0.0f, mx = -3.402823e38f;
    int cnt = 0;
    for (int n = n0; n < n1; ++n) {
        int g = batch[n];
        if (g != gcur) {
            atomicAdd(&psum[gcur * HID + lane], sum);
            atomicMax(&pmax[gcur * HID + lane], enc_f(mx));
            if (lane == 0) atomicAdd(&pcnt[gcur], (float)cnt);
            gcur = g; sum = 0.0f; mx = -3.402823e38f; cnt = 0;
        }
        float v = __half2float(x[(size_t)n * HID + lane]);
        sum += v;
        mx = fmaxf(mx, v);
        ++cnt;
    }
    atomicAdd(&psum[gcur * HID + lane], sum);
    atomicMax(&pmax[gcur * HID + lane], enc_f(mx));
    if (lane == 0) atomicAdd(&pcnt[gcur], (float)cnt);
}

__global__ __launch_bounds__(64) void classifier_pass(
        const float* __restrict__ psum, const unsigned* __restrict__ pmax,
        const float* __restrict__ pcnt,
        const float* __restrict__ CW1, const float* __restrict__ Cb1,
        const float* __restrict__ CW2, const float* __restrict__ Cb2,
        float* __restrict__ out) {
    int g = blockIdx.x, j = threadIdx.x;
    __shared__ float pooled[2 * HID];
    __shared__ float hsh[HID];
    float gc = fmaxf(pcnt[g], 1.0f);
    pooled[j] = psum[g * HID + j] / gc;
    pooled[HID + j] = dec_f(pmax[g * HID + j]);
    __syncthreads();
    float acc = Cb1[j];
    #pragma unroll 8
    for (int k = 0; k < 2 * HID; ++k) acc = fmaf(pooled[k], CW1[k * HID + j], acc);
    hsh[j] = fmaxf(acc, 0.0f);
    __syncthreads();
    if (j < NCLS) {
        float o = Cb2[j];
        #pragma unroll 8
        for (int k = 0; k < HID; ++k) o = fmaf(hsh[k], CW2[k * NCLS + j], o);
        out[g * NCLS + j] = o;
    }
}

// ---------- launch ----------

extern "C" void kernel_launch(void* const* d_in, const int* in_sizes, int n_in,
                              void* d_out, int out_size, void* d_ws, size_t ws_size,
                              hipStream_t stream) {
    const int*   ei        = (const int*)d_in[0];
    const int*   ports     = (const int*)d_in[1];
    const int*   flags     = (const int*)d_in[2];
    const float* eattr     = (const float*)d_in[3];
    const int*   batch     = (const int*)d_in[4];
    const float* emb_port  = (const float*)d_in[5];
    const float* emb_flags = (const float*)d_in[6];
    const float* W1  = (const float*)d_in[7];
    const float* b1  = (const float*)d_in[8];
    const float* W2  = (const float*)d_in[9];
    const float* b2  = (const float*)d_in[10];
    const float* CW1 = (const float*)d_in[11];
    const float* Cb1 = (const float*)d_in[12];
    const float* CW2 = (const float*)d_in[13];
    const float* Cb2 = (const float*)d_in[14];
    float* outp = (float*)d_out;

    const int E = in_sizes[0] / 2;
    const int N = in_sizes[4];
    const int B = out_size / NCLS;
    const int NB = (N + 255) / 256;     // scan blocks (must be <= 512)

    // ---- workspace layout (~137 MB; proven-safe budget >= 142 MB) ----
    char* w = (char*)d_ws;
    __half*   xA   = (__half*)w;  w += (size_t)N * HID * 2;
    __half*   xB   = (__half*)w;  w += (size_t)N * HID * 2;
    float*    s    = (float*)w;   w += (size_t)N * HID * 4;
    int4*     rec  = (int4*)w;    w += (size_t)E * 16;     // packed sorted records
    int*      srcs = (int*)w;     w += (size_t)E * 4;      // contiguous src ids
    int*      rank = (int*)w;     w += (size_t)E * 4;      // rank within col
    int*      offs = (int*)w;     w += (size_t)N * 4;
    int*      loc  = (int*)w;     w += (size_t)N * 4;
    int*      deg  = (int*)w;     w += (size_t)N * 4;      // packed degree copy
    int*      part = (int*)w;     w += 512 * 4;
    // zero region (single memset): hist(padded), hsum, lsum, psum, pmax, pcnt
    char* zero_base = w;
    int*      hist = (int*)w;     w += (size_t)N * CPAD * 4; // PADDED (1/line)
    float*    hsum = (float*)w;   w += (size_t)N * HID * 4;
    float*    lsum = (float*)w;   w += (size_t)N * IN_DIM * 4;
    float*    psum = (float*)w;   w += (size_t)B * HID * 4;
    unsigned* pmax = (unsigned*)w; w += (size_t)B * HID * 4;
    float*    pcnt = (float*)w;   w += (size_t)B * 4;
    size_t zero_bytes = (size_t)(w - zero_base);

    hipMemsetAsync(zero_base, 0, zero_bytes, stream);

    // CSR build: ONE atomic pass (hist captures rank); sort is atomic-free
    hist_pass<<<(E + 255) / 256, 256, 0, stream>>>(ei, hist, rank, E);
    scan1<<<NB, 256, 0, stream>>>(hist, loc, part, deg, N);
    scan2<<<1, 512, 0, stream>>>(part, NB);
    scan3<<<NB, 256, 0, stream>>>(loc, part, offs, N);
    sort_pass<<<(E + 255) / 256, 256, 0, stream>>>(
        ei, ports, flags, offs, rank, rec, srcs, E);

    // edge hidden-layer + segmented reduction -> hsum, lsum (single
    // full-E dispatch: the half-E split's drain tail cost ~48us)
    edge_hidden_reduce<<<(E + BLK - 1) / BLK, BLK, 0, stream>>>(
        rec, eattr, emb_port, emb_flags, W1, b1, hsum, lsum, E);

    // per-node: self-loop hidden + W2 -> s, x1 (fp16); NPW nodes/wave
    node_mlp<<<(N + NPW * 4 - 1) / (NPW * 4), 256, 0, stream>>>(
        lsum, hsum, deg, W1, b1, W2, b2, s, xA, N);

    // layers 2 and 3 (fp16 state, fp32 accumulate)
    gather_layer<<<(N + 3) / 4, 256, 0, stream>>>(
        offs, deg, srcs, xA, s, xB, N);
    gather_layer<<<(N + 3) / 4, 256, 0, stream>>>(
        offs, deg, srcs, xB, s, xA, N);

    // pooling + classifier
    pool_pass<<<((N + 63) / 64 * 64 + 255) / 256, 256, 0, stream>>>(
        xA, batch, psum, pmax, pcnt, N);
    classifier_pass<<<B, 64, 0, stream>>>(psum, pmax, pcnt, CW1, Cb1, CW2, Cb2, outp);
}